// Round 8
// baseline (371.868 us; speedup 1.0000x reference)
//
#include <hip/hip_runtime.h>

#define T_TOK 1024
#define Dm 768
#define Hm 3072
#define NE 8
#define NPACK 3072      // 2048 expert-selected rows + 1024 shared rows
#define MAXTILES 32

typedef __attribute__((ext_vector_type(8))) short short8;
typedef __attribute__((ext_vector_type(4))) float f32x4;

__device__ __forceinline__ unsigned f2bf(float f) {
  unsigned u = __builtin_bit_cast(unsigned, f);
  u += 0x7fffu + ((u >> 16) & 1u);
  return u >> 16;
}
__device__ __forceinline__ unsigned pk2bf(float a, float b) {
  return f2bf(a) | (f2bf(b) << 16);
}

// ---------------- Router: logits = x @ Wr^T, top-2, softmax, compact ----------------
__global__ __launch_bounds__(256) void router_kernel(
    const float* __restrict__ x, const float* __restrict__ Wr,
    int* __restrict__ counts, int* __restrict__ tlist, float* __restrict__ glist,
    int4* __restrict__ tok2row, float2* __restrict__ tok2g) {
  __shared__ float sWr[NE * Dm];  // 24 KB
  for (int i = threadIdx.x; i < NE * Dm; i += 256) sWr[i] = Wr[i];
  __syncthreads();
  const int wave = threadIdx.x >> 6, lane = threadIdx.x & 63;
  const int t = blockIdx.x * 4 + wave;
  float acc[NE];
#pragma unroll
  for (int e = 0; e < NE; e++) acc[e] = 0.f;
  for (int d = lane; d < Dm; d += 64) {
    float xv = x[t * Dm + d];
#pragma unroll
    for (int e = 0; e < NE; e++) acc[e] += xv * sWr[e * Dm + d];
  }
#pragma unroll
  for (int e = 0; e < NE; e++) {
#pragma unroll
    for (int off = 32; off > 0; off >>= 1) acc[e] += __shfl_down(acc[e], off);
  }
  if (lane == 0) {
    int i0 = 0; float v0 = acc[0];
#pragma unroll
    for (int e = 1; e < NE; e++) if (acc[e] > v0) { v0 = acc[e]; i0 = e; }
    int i1 = -1; float v1 = -1e30f;
#pragma unroll
    for (int e = 0; e < NE; e++) if (e != i0 && acc[e] > v1) { v1 = acc[e]; i1 = e; }
    float g0 = 1.f / (1.f + expf(v1 - v0));
    float g1 = 1.f - g0;
    int p0 = atomicAdd(&counts[i0], 1);
    tlist[i0 * T_TOK + p0] = t; glist[i0 * T_TOK + p0] = g0;
    int p1 = atomicAdd(&counts[i1], 1);
    tlist[i1 * T_TOK + p1] = t; glist[i1 * T_TOK + p1] = g1;
    tok2row[t] = make_int4(i0, p0, i1, p1);
    tok2g[t] = float2{g0, g1};
  }
}

// ---------------- Packed-M bf16 MFMA GEMM, 128x128 tile, BK=64, 8 waves ----------------
// Tile map derived per-block from counts (no prefix dispatch).
// MODE 0: h[prow] = relu(gather(x) @ W1^T + b1)   K=768,        N=3072 -> hbuf bf16
// MODE 1: ybuf[z][prow] = h[prow] @ W2^T          K=1536/chunk, N=768  -> f32 store
// MODE 2: out[tok] += gate*(h @ W2^T + b2)        (fallback if ws too small) atomicAdd
template <int MODE>
__global__ __launch_bounds__(512) void moe_gemm(
    const float* __restrict__ x,
    const float* __restrict__ W1, const float* __restrict__ b1,
    const float* __restrict__ sW1, const float* __restrict__ sb1,
    const float* __restrict__ W2, const float* __restrict__ b2,
    const float* __restrict__ sW2, const float* __restrict__ sb2,
    unsigned short* __restrict__ hbuf, float* __restrict__ ybuf, float* __restrict__ outp,
    const int* __restrict__ counts,
    const int* __restrict__ tlist, const float* __restrict__ glist) {
  // ---- derive (e, m0, pbase, Ne) from counts ----
  int ti = blockIdx.y;
  int e = 0, m0 = 0, pbase = 0, Ne = 0;
  bool found = false;
  for (int ee = 0; ee <= NE; ee++) {
    int ne = (ee < NE) ? counts[ee] : T_TOK;
    int nt = (ne + 127) >> 7;
    if (!found) {
      if (ti < nt) { e = ee; Ne = ne; m0 = ti << 7; found = true; }
      else { ti -= nt; pbase += ne; }
    }
  }
  if (!found) return;
  const int n0 = blockIdx.x * 128;

  constexpr int Kfull = (MODE == 0) ? Dm : Hm;        // stride of B rows
  constexpr int KC    = (MODE == 0) ? Dm : (Hm / 2);  // K span per block
  constexpr int NK    = KC / 64;                      // 12 or 24 (even)
  const int kbase = (MODE == 0) ? 0 : (blockIdx.z * KC);

  const float* Bw;
  const float* bias;
  if constexpr (MODE == 0) {
    Bw   = (e < NE) ? W1 + (size_t)e * Hm * Dm : sW1;
    bias = (e < NE) ? b1 + (size_t)e * Hm : sb1;
  } else {
    Bw   = (e < NE) ? W2 + (size_t)e * Dm * Hm : sW2;
    bias = (e < NE) ? b2 + (size_t)e * Dm : sb2;
  }

  __shared__ unsigned short sA[128][72];
  __shared__ unsigned short sB[128][72];

  const int tid = threadIdx.x;
  const int lane = tid & 63;
  const int wid = tid >> 6;          // 0..7
  const int wr = wid >> 2;           // 0..1 -> 64 rows
  const int wc = wid & 3;            // 0..3 -> 32 cols

  // ---- staging pointers (col offset folded in) ----
  const float* aPtrF[4];
  const unsigned short* aPtrH[2];
  if constexpr (MODE == 0) {
#pragma unroll
    for (int c = 0; c < 4; c++) {
      int gi = m0 + c * 32 + (tid >> 4);
      int si = gi < Ne ? gi : Ne - 1;
      int tok = (e < NE) ? tlist[e * T_TOK + si] : si;
      aPtrF[c] = x + (size_t)tok * Dm + (tid & 15) * 4;
    }
  } else {
#pragma unroll
    for (int c = 0; c < 2; c++) {
      int prow = pbase + m0 + c * 64 + (tid >> 3);
      if (prow >= NPACK) prow = NPACK - 1;
      aPtrH[c] = hbuf + (size_t)prow * Hm + kbase + (tid & 7) * 8;
    }
  }
  const float* bPtrF[4];
#pragma unroll
  for (int c = 0; c < 4; c++) {
    int nrow = n0 + c * 32 + (tid >> 4);
    bPtrF[c] = Bw + (size_t)nrow * Kfull + kbase + (tid & 15) * 4;
  }

  f32x4 acc[4][2];
#pragma unroll
  for (int m = 0; m < 4; m++)
#pragma unroll
    for (int n = 0; n < 2; n++) acc[m][n] = (f32x4)0.0f;

  const int rF = tid >> 4;        // f32 staging row base (0..31)
  const int cF = (tid & 15) * 4;  // f32 staging col (shorts)
  const int rH = tid >> 3;        // bf16 staging row base (0..63)
  const int cH = (tid & 7) * 8;   // bf16 staging col
  const int frow = lane & 15;
  const int fk = (lane >> 4) * 8;

  // ---- two named staging groups (2-deep pipeline; static indexing) ----
  float4 aFA[4], bFA[4], aFB[4], bFB[4];
  uint4 aHA[2], aHB[2];

  auto stage_load_A = [&](int ko) {
    if constexpr (MODE == 0) {
#pragma unroll
      for (int c = 0; c < 4; c++) aFA[c] = *(const float4*)(aPtrF[c] + ko);
    } else {
#pragma unroll
      for (int c = 0; c < 2; c++) aHA[c] = *(const uint4*)(aPtrH[c] + ko);
    }
#pragma unroll
    for (int c = 0; c < 4; c++) bFA[c] = *(const float4*)(bPtrF[c] + ko);
  };
  auto stage_load_B = [&](int ko) {
    if constexpr (MODE == 0) {
#pragma unroll
      for (int c = 0; c < 4; c++) aFB[c] = *(const float4*)(aPtrF[c] + ko);
    } else {
#pragma unroll
      for (int c = 0; c < 2; c++) aHB[c] = *(const uint4*)(aPtrH[c] + ko);
    }
#pragma unroll
    for (int c = 0; c < 4; c++) bFB[c] = *(const float4*)(bPtrF[c] + ko);
  };
  auto stage_write_A = [&]() {
    if constexpr (MODE == 0) {
#pragma unroll
      for (int c = 0; c < 4; c++)
        *(uint2*)&sA[c * 32 + rF][cF] =
            make_uint2(pk2bf(aFA[c].x, aFA[c].y), pk2bf(aFA[c].z, aFA[c].w));
    } else {
#pragma unroll
      for (int c = 0; c < 2; c++) *(uint4*)&sA[c * 64 + rH][cH] = aHA[c];
    }
#pragma unroll
    for (int c = 0; c < 4; c++)
      *(uint2*)&sB[c * 32 + rF][cF] =
          make_uint2(pk2bf(bFA[c].x, bFA[c].y), pk2bf(bFA[c].z, bFA[c].w));
  };
  auto stage_write_B = [&]() {
    if constexpr (MODE == 0) {
#pragma unroll
      for (int c = 0; c < 4; c++)
        *(uint2*)&sA[c * 32 + rF][cF] =
            make_uint2(pk2bf(aFB[c].x, aFB[c].y), pk2bf(aFB[c].z, aFB[c].w));
    } else {
#pragma unroll
      for (int c = 0; c < 2; c++) *(uint4*)&sA[c * 64 + rH][cH] = aHB[c];
    }
#pragma unroll
    for (int c = 0; c < 4; c++)
      *(uint2*)&sB[c * 32 + rF][cF] =
          make_uint2(pk2bf(bFB[c].x, bFB[c].y), pk2bf(bFB[c].z, bFB[c].w));
  };
  auto do_mfma = [&]() {
#pragma unroll
    for (int kk = 0; kk < 2; kk++) {
      short8 af[4], bfr[2];
#pragma unroll
      for (int m = 0; m < 4; m++)
        af[m] = *(const short8*)&sA[wr * 64 + m * 16 + frow][kk * 32 + fk];
#pragma unroll
      for (int n = 0; n < 2; n++)
        bfr[n] = *(const short8*)&sB[wc * 32 + n * 16 + frow][kk * 32 + fk];
#pragma unroll
      for (int m = 0; m < 4; m++)
#pragma unroll
        for (int n = 0; n < 2; n++)
          acc[m][n] = __builtin_amdgcn_mfma_f32_16x16x32_bf16(af[m], bfr[n], acc[m][n], 0, 0, 0);
    }
  };

  // prologue: tiles 0 and 1 in flight
  stage_load_A(0);
  stage_load_B(64);

  for (int ks = 0; ks < NK; ks += 2) {
    // ---- phase A: tile ks ----
    stage_write_A();
    __syncthreads();
    if (ks + 2 < NK) stage_load_A((ks + 2) * 64);
    do_mfma();
    __syncthreads();
    // ---- phase B: tile ks+1 ----
    stage_write_B();
    __syncthreads();
    if (ks + 3 < NK) stage_load_B((ks + 3) * 64);
    do_mfma();
    __syncthreads();
  }

  // ---- epilogue ----
#pragma unroll
  for (int m = 0; m < 4; m++) {
    int lr = wr * 64 + m * 16 + (lane >> 4) * 4;
#pragma unroll
    for (int n = 0; n < 2; n++) {
      int gc = n0 + wc * 32 + n * 16 + (lane & 15);
      float bv = bias[gc];
#pragma unroll
      for (int j = 0; j < 4; j++) {
        int gi = m0 + lr + j;
        if (gi >= Ne) continue;
        float v = acc[m][n][j];
        if constexpr (MODE == 0) {
          v += bv;
          v = v > 0.f ? v : 0.f;
          hbuf[(size_t)(pbase + gi) * Hm + gc] = (unsigned short)f2bf(v);
        } else if constexpr (MODE == 1) {
          ybuf[(size_t)blockIdx.z * NPACK * Dm + (size_t)(pbase + gi) * Dm + gc] = v;
        } else {
          int t; float g;
          if (e < NE) { t = tlist[e * T_TOK + gi]; g = glist[e * T_TOK + gi]; }
          else        { t = gi; g = 0.2f; }
          float add = g * (v + (kbase == 0 ? bv : 0.f));
          atomicAdd(&outp[(size_t)t * Dm + gc], add);
        }
      }
    }
  }
}

// ---------------- Finalize: gather per-token rows, apply gates + biases ----------------
__global__ __launch_bounds__(256) void finalize_kernel(
    const float* __restrict__ ybuf, const int* __restrict__ counts,
    const int4* __restrict__ tok2row, const float2* __restrict__ tok2g,
    const float* __restrict__ b2, const float* __restrict__ sb2,
    float* __restrict__ out) {
  const int t = blockIdx.x;
  int bases[NE];
  int s = 0;
#pragma unroll
  for (int e = 0; e < NE; e++) { bases[e] = s; s += counts[e]; }
  const int4 rr = tok2row[t];
  const float2 gg = tok2g[t];
  const int r0 = bases[rr.x] + rr.y;
  const int r1 = bases[rr.z] + rr.w;
  const int rs = s + t;  // shared rows start at s (==2048)
  const float* y0 = ybuf;
  const float* y1 = ybuf + (size_t)NPACK * Dm;
  for (int d = threadIdx.x; d < Dm; d += 256) {
    float v0 = y0[(size_t)r0 * Dm + d] + y1[(size_t)r0 * Dm + d] + b2[rr.x * Dm + d];
    float v1 = y0[(size_t)r1 * Dm + d] + y1[(size_t)r1 * Dm + d] + b2[rr.z * Dm + d];
    float vs = y0[(size_t)rs * Dm + d] + y1[(size_t)rs * Dm + d] + sb2[d];
    out[(size_t)t * Dm + d] = gg.x * v0 + gg.y * v1 + 0.2f * vs;
  }
}

extern "C" void kernel_launch(void* const* d_in, const int* in_sizes, int n_in,
                              void* d_out, int out_size, void* d_ws, size_t ws_size,
                              hipStream_t stream) {
  const float* x   = (const float*)d_in[0];
  const float* Wr  = (const float*)d_in[1];
  const float* W1  = (const float*)d_in[2];
  const float* b1  = (const float*)d_in[3];
  const float* W2  = (const float*)d_in[4];
  const float* b2  = (const float*)d_in[5];
  const float* sW1 = (const float*)d_in[6];
  const float* sb1 = (const float*)d_in[7];
  const float* sW2 = (const float*)d_in[8];
  const float* sb2 = (const float*)d_in[9];
  float* out = (float*)d_out;

  char* ws = (char*)d_ws;
  int*    counts  = (int*)(ws + 0);              // 128 B
  int4*   tok2row = (int4*)(ws + 1024);          // 16 KB -> 17408
  float2* tok2g   = (float2*)(ws + 17408);       // 8 KB  -> 25600
  int*    tlist   = (int*)(ws + 25600);          // 32 KB -> 58368
  float*  glist   = (float*)(ws + 58368);        // 32 KB -> 91136
  unsigned short* hbuf = (unsigned short*)(ws + 91136);      // 18,874,368 -> 18,965,504
  float*  ybuf    = (float*)(ws + 18965504);     // 2*3072*768*4 = 18,874,368 -> 37,839,872
  const size_t NEED_YBUF = 37839872;

  (void)hipMemsetAsync(counts, 0, 128, stream);

  router_kernel<<<dim3(T_TOK / 4), 256, 0, stream>>>(x, Wr, counts, tlist, glist,
                                                     tok2row, tok2g);

  // GEMM1: packed rows (experts + shared) x W1^T, relu, -> hbuf bf16
  moe_gemm<0><<<dim3(Hm / 128, MAXTILES, 1), 512, 0, stream>>>(
      x, W1, b1, sW1, sb1, W2, b2, sW2, sb2, hbuf, ybuf, out, counts, tlist, glist);

  if (ws_size >= NEED_YBUF) {
    // GEMM2: hbuf x W2^T, split-K=2 -> ybuf f32 chunks; finalize gathers
    moe_gemm<1><<<dim3(Dm / 128, MAXTILES, 2), 512, 0, stream>>>(
        x, W1, b1, sW1, sb1, W2, b2, sW2, sb2, hbuf, ybuf, out, counts, tlist, glist);
    finalize_kernel<<<dim3(T_TOK), 256, 0, stream>>>(ybuf, counts, tok2row, tok2g,
                                                     b2, sb2, out);
  } else {
    (void)hipMemsetAsync(out, 0, (size_t)T_TOK * Dm * sizeof(float), stream);
    moe_gemm<2><<<dim3(Dm / 128, MAXTILES, 2), 512, 0, stream>>>(
        x, W1, b1, sW1, sb1, W2, b2, sW2, sb2, hbuf, ybuf, out, counts, tlist, glist);
  }
}

// Round 9
// 356.643 us; speedup vs baseline: 1.0427x; 1.0427x over previous
//
#include <hip/hip_runtime.h>

#define T_TOK 1024
#define Dm 768
#define Hm 3072
#define NE 8
#define NPACK 3072      // 2048 expert-selected rows + 1024 shared rows
#define MAXTILES 32

typedef __attribute__((ext_vector_type(8))) short short8;
typedef __attribute__((ext_vector_type(4))) float f32x4;

__device__ __forceinline__ unsigned f2bf(float f) {
  unsigned u = __builtin_bit_cast(unsigned, f);
  u += 0x7fffu + ((u >> 16) & 1u);
  return u >> 16;
}
__device__ __forceinline__ unsigned pk2bf(float a, float b) {
  return f2bf(a) | (f2bf(b) << 16);
}
__device__ __forceinline__ float bf2f(unsigned short s) {
  unsigned u = ((unsigned)s) << 16;
  return __builtin_bit_cast(float, u);
}

// ---------------- Router: logits = x @ Wr^T, top-2, softmax, compact ----------------
__global__ __launch_bounds__(256) void router_kernel(
    const float* __restrict__ x, const float* __restrict__ Wr,
    int* __restrict__ counts, int* __restrict__ tlist,
    int4* __restrict__ tok2row, float2* __restrict__ tok2g) {
  __shared__ float sWr[NE * Dm];  // 24 KB
  for (int i = threadIdx.x; i < NE * Dm; i += 256) sWr[i] = Wr[i];
  __syncthreads();
  const int wave = threadIdx.x >> 6, lane = threadIdx.x & 63;
  const int t = blockIdx.x * 4 + wave;
  float acc[NE];
#pragma unroll
  for (int e = 0; e < NE; e++) acc[e] = 0.f;
  for (int d = lane; d < Dm; d += 64) {
    float xv = x[t * Dm + d];
#pragma unroll
    for (int e = 0; e < NE; e++) acc[e] += xv * sWr[e * Dm + d];
  }
#pragma unroll
  for (int e = 0; e < NE; e++) {
#pragma unroll
    for (int off = 32; off > 0; off >>= 1) acc[e] += __shfl_down(acc[e], off);
  }
  if (lane == 0) {
    int i0 = 0; float v0 = acc[0];
#pragma unroll
    for (int e = 1; e < NE; e++) if (acc[e] > v0) { v0 = acc[e]; i0 = e; }
    int i1 = -1; float v1 = -1e30f;
#pragma unroll
    for (int e = 0; e < NE; e++) if (e != i0 && acc[e] > v1) { v1 = acc[e]; i1 = e; }
    float g0 = 1.f / (1.f + expf(v1 - v0));
    float g1 = 1.f - g0;
    int p0 = atomicAdd(&counts[i0], 1);
    tlist[i0 * T_TOK + p0] = t;
    int p1 = atomicAdd(&counts[i1], 1);
    tlist[i1 * T_TOK + p1] = t;
    tok2row[t] = make_int4(i0, p0, i1, p1);
    tok2g[t] = float2{g0, g1};
  }
}

// ---------------- Packed-M bf16 MFMA GEMM, BK=64, 8 waves, XCD-swizzled ----------------
// MODE 0: BN=128, grid 768 (24 n x 32 ti):  h = relu(gather(x) @ W1^T + b1) -> hbuf bf16
//         swizzle: nIdx=(b%8)+8*((b/8)%3), ti=b/24  => same-n blocks share an XCD L2.
// MODE 1: BN=96,  grid 256 (8 n x 32 ti):   experts: ybuf = h @ W2^T (bf16, no bias)
//                                           shared:  out  = 0.2*(h @ sW2^T + sb2)
//         swizzle: nIdx=b%8, ti=b/8         => same-n blocks share an XCD L2.
template <int MODE>
__global__ __launch_bounds__(512) void moe_gemm(
    const float* __restrict__ x,
    const float* __restrict__ W1, const float* __restrict__ b1,
    const float* __restrict__ sW1, const float* __restrict__ sb1,
    const float* __restrict__ W2, const float* __restrict__ sW2,
    const float* __restrict__ sb2,
    unsigned short* __restrict__ hbuf, unsigned short* __restrict__ ybuf,
    float* __restrict__ outp,
    const int* __restrict__ counts, const int* __restrict__ tlist) {
  constexpr int BN    = (MODE == 0) ? 128 : 96;
  constexpr int Kfull = (MODE == 0) ? Dm : Hm;
  constexpr int NK    = Kfull / 64;          // 12 or 48 (both even)
  constexpr int M_REP = (MODE == 0) ? 4 : 2;
  constexpr int N_REP = (MODE == 0) ? 2 : 3;
  constexpr int NBR   = BN / 32;             // B staging float4 rows: 4 or 3

  const int b = blockIdx.x;
  int nIdx, ti;
  if constexpr (MODE == 0) { nIdx = (b % 8) + 8 * ((b / 8) % 3); ti = b / 24; }
  else                     { nIdx = b % 8;                        ti = b / 8;  }
  const int n0 = nIdx * BN;

  // ---- derive (e, m0, pbase, Ne) from counts ----
  int e = 0, m0 = 0, pbase = 0, Ne = 0;
  bool found = false;
  for (int ee = 0; ee <= NE; ee++) {
    int ne = (ee < NE) ? counts[ee] : T_TOK;
    int nt = (ne + 127) >> 7;
    if (!found) {
      if (ti < nt) { e = ee; Ne = ne; m0 = ti << 7; found = true; }
      else { ti -= nt; pbase += ne; }
    }
  }
  if (!found) return;

  const float* Bw;
  const float* bias;
  if constexpr (MODE == 0) {
    Bw   = (e < NE) ? W1 + (size_t)e * Hm * Dm : sW1;
    bias = (e < NE) ? b1 + (size_t)e * Hm : sb1;
  } else {
    Bw   = (e < NE) ? W2 + (size_t)e * Dm * Hm : sW2;
    bias = sb2;   // used only for the shared segment
  }

  __shared__ unsigned short sA[128][72];
  __shared__ unsigned short sB[BN][72];

  const int tid = threadIdx.x;
  const int lane = tid & 63;
  const int wid = tid >> 6;  // 0..7
  int rb, cb;
  if constexpr (MODE == 0) { rb = (wid >> 2) * 64; cb = (wid & 3) * 32; }
  else                     { rb = (wid >> 1) * 32; cb = (wid & 1) * 48; }

  // ---- staging pointers (col offset folded in) ----
  const float* aPtrF[4];
  const unsigned short* aPtrH[2];
  if constexpr (MODE == 0) {
#pragma unroll
    for (int c = 0; c < 4; c++) {
      int gi = m0 + c * 32 + (tid >> 4);
      int si = gi < Ne ? gi : Ne - 1;
      int tok = (e < NE) ? tlist[e * T_TOK + si] : si;
      aPtrF[c] = x + (size_t)tok * Dm + (tid & 15) * 4;
    }
  } else {
#pragma unroll
    for (int c = 0; c < 2; c++) {
      int prow = pbase + m0 + c * 64 + (tid >> 3);
      if (prow >= NPACK) prow = NPACK - 1;
      aPtrH[c] = hbuf + (size_t)prow * Hm + (tid & 7) * 8;
    }
  }
  const float* bPtrF[NBR];
#pragma unroll
  for (int c = 0; c < NBR; c++) {
    int nrow = n0 + c * 32 + (tid >> 4);
    bPtrF[c] = Bw + (size_t)nrow * Kfull + (tid & 15) * 4;
  }

  f32x4 acc[M_REP][N_REP];
#pragma unroll
  for (int m = 0; m < M_REP; m++)
#pragma unroll
    for (int n = 0; n < N_REP; n++) acc[m][n] = (f32x4)0.0f;

  const int rF = tid >> 4;        // f32 staging row base (0..31)
  const int cF = (tid & 15) * 4;  // f32 staging col (shorts)
  const int rH = tid >> 3;        // bf16 staging row base (0..63)
  const int cH = (tid & 7) * 8;   // bf16 staging col
  const int frow = lane & 15;
  const int fk = (lane >> 4) * 8;

  // ---- two named staging groups (2-deep; static indexing) ----
  float4 aFA[4], bFA[NBR], aFB[4], bFB[NBR];
  uint4 aHA[2], aHB[2];

  auto stage_load_A = [&](int ko) {
    if constexpr (MODE == 0) {
#pragma unroll
      for (int c = 0; c < 4; c++) aFA[c] = *(const float4*)(aPtrF[c] + ko);
    } else {
#pragma unroll
      for (int c = 0; c < 2; c++) aHA[c] = *(const uint4*)(aPtrH[c] + ko);
    }
#pragma unroll
    for (int c = 0; c < NBR; c++) bFA[c] = *(const float4*)(bPtrF[c] + ko);
  };
  auto stage_load_B = [&](int ko) {
    if constexpr (MODE == 0) {
#pragma unroll
      for (int c = 0; c < 4; c++) aFB[c] = *(const float4*)(aPtrF[c] + ko);
    } else {
#pragma unroll
      for (int c = 0; c < 2; c++) aHB[c] = *(const uint4*)(aPtrH[c] + ko);
    }
#pragma unroll
    for (int c = 0; c < NBR; c++) bFB[c] = *(const float4*)(bPtrF[c] + ko);
  };
  auto stage_write_A = [&]() {
    if constexpr (MODE == 0) {
#pragma unroll
      for (int c = 0; c < 4; c++)
        *(uint2*)&sA[c * 32 + rF][cF] =
            make_uint2(pk2bf(aFA[c].x, aFA[c].y), pk2bf(aFA[c].z, aFA[c].w));
    } else {
#pragma unroll
      for (int c = 0; c < 2; c++) *(uint4*)&sA[c * 64 + rH][cH] = aHA[c];
    }
#pragma unroll
    for (int c = 0; c < NBR; c++)
      *(uint2*)&sB[c * 32 + rF][cF] =
          make_uint2(pk2bf(bFA[c].x, bFA[c].y), pk2bf(bFA[c].z, bFA[c].w));
  };
  auto stage_write_B = [&]() {
    if constexpr (MODE == 0) {
#pragma unroll
      for (int c = 0; c < 4; c++)
        *(uint2*)&sA[c * 32 + rF][cF] =
            make_uint2(pk2bf(aFB[c].x, aFB[c].y), pk2bf(aFB[c].z, aFB[c].w));
    } else {
#pragma unroll
      for (int c = 0; c < 2; c++) *(uint4*)&sA[c * 64 + rH][cH] = aHB[c];
    }
#pragma unroll
    for (int c = 0; c < NBR; c++)
      *(uint2*)&sB[c * 32 + rF][cF] =
          make_uint2(pk2bf(bFB[c].x, bFB[c].y), pk2bf(bFB[c].z, bFB[c].w));
  };
  auto do_mfma = [&]() {
#pragma unroll
    for (int kk = 0; kk < 2; kk++) {
      short8 af[M_REP], bfr[N_REP];
#pragma unroll
      for (int m = 0; m < M_REP; m++)
        af[m] = *(const short8*)&sA[rb + m * 16 + frow][kk * 32 + fk];
#pragma unroll
      for (int n = 0; n < N_REP; n++)
        bfr[n] = *(const short8*)&sB[cb + n * 16 + frow][kk * 32 + fk];
#pragma unroll
      for (int m = 0; m < M_REP; m++)
#pragma unroll
        for (int n = 0; n < N_REP; n++)
          acc[m][n] = __builtin_amdgcn_mfma_f32_16x16x32_bf16(af[m], bfr[n], acc[m][n], 0, 0, 0);
    }
  };

  stage_load_A(0);
  stage_load_B(64);

  for (int ks = 0; ks < NK; ks += 2) {
    stage_write_A();
    __syncthreads();
    if (ks + 2 < NK) stage_load_A((ks + 2) * 64);
    do_mfma();
    __syncthreads();
    stage_write_B();
    __syncthreads();
    if (ks + 3 < NK) stage_load_B((ks + 3) * 64);
    do_mfma();
    __syncthreads();
  }

  // ---- epilogue ----
#pragma unroll
  for (int m = 0; m < M_REP; m++) {
    int lr = rb + m * 16 + (lane >> 4) * 4;
#pragma unroll
    for (int n = 0; n < N_REP; n++) {
      int gc = n0 + cb + n * 16 + (lane & 15);
#pragma unroll
      for (int j = 0; j < 4; j++) {
        int gi = m0 + lr + j;
        if (gi >= Ne) continue;
        float v = acc[m][n][j];
        if constexpr (MODE == 0) {
          v += bias[gc];
          v = v > 0.f ? v : 0.f;
          hbuf[(size_t)(pbase + gi) * Hm + gc] = (unsigned short)f2bf(v);
        } else {
          if (e < NE) {
            ybuf[(size_t)(pbase + gi) * Dm + gc] = (unsigned short)f2bf(v);
          } else {
            outp[(size_t)gi * Dm + gc] = 0.2f * (v + bias[gc]);
          }
        }
      }
    }
  }
}

// ---------------- Finalize: out += g0*(y[r0]+b2[e0]) + g1*(y[r1]+b2[e1]) ----------------
__global__ __launch_bounds__(256) void finalize_kernel(
    const unsigned short* __restrict__ ybuf, const int* __restrict__ counts,
    const int4* __restrict__ tok2row, const float2* __restrict__ tok2g,
    const float* __restrict__ b2, float* __restrict__ out) {
  const int t = blockIdx.x;
  int bases[NE];
  int s = 0;
#pragma unroll
  for (int e = 0; e < NE; e++) { bases[e] = s; s += counts[e]; }
  const int4 rr = tok2row[t];
  const float2 gg = tok2g[t];
  const int r0 = bases[rr.x] + rr.y;
  const int r1 = bases[rr.z] + rr.w;
  for (int d = threadIdx.x; d < Dm; d += 256) {
    float v0 = bf2f(ybuf[(size_t)r0 * Dm + d]) + b2[rr.x * Dm + d];
    float v1 = bf2f(ybuf[(size_t)r1 * Dm + d]) + b2[rr.z * Dm + d];
    out[(size_t)t * Dm + d] += gg.x * v0 + gg.y * v1;
  }
}

extern "C" void kernel_launch(void* const* d_in, const int* in_sizes, int n_in,
                              void* d_out, int out_size, void* d_ws, size_t ws_size,
                              hipStream_t stream) {
  const float* x   = (const float*)d_in[0];
  const float* Wr  = (const float*)d_in[1];
  const float* W1  = (const float*)d_in[2];
  const float* b1  = (const float*)d_in[3];
  const float* W2  = (const float*)d_in[4];
  const float* b2  = (const float*)d_in[5];
  const float* sW1 = (const float*)d_in[6];
  const float* sb1 = (const float*)d_in[7];
  const float* sW2 = (const float*)d_in[8];
  const float* sb2 = (const float*)d_in[9];
  float* out = (float*)d_out;

  char* ws = (char*)d_ws;
  int*    counts  = (int*)(ws + 0);              // 128 B
  int4*   tok2row = (int4*)(ws + 128);           // 16 KB -> 16512
  float2* tok2g   = (float2*)(ws + 16512);       // 8 KB  -> 24704
  int*    tlist   = (int*)(ws + 24704);          // 32 KB -> 57472
  unsigned short* hbuf = (unsigned short*)(ws + 57472);      // 3072*3072*2 -> 18,931,840
  unsigned short* ybuf = (unsigned short*)(ws + 18931840);   // 2048*768*2  -> 22,077,568
  // total 22,077,568 B <= 22,085,888 proven by round-1's passing layout.

  (void)hipMemsetAsync(counts, 0, 128, stream);

  router_kernel<<<dim3(T_TOK / 4), 256, 0, stream>>>(x, Wr, counts, tlist, tok2row, tok2g);

  // GEMM1: packed rows (experts + shared) x W1^T, relu -> hbuf bf16
  moe_gemm<0><<<dim3(24 * MAXTILES), 512, 0, stream>>>(
      x, W1, b1, sW1, sb1, W2, sW2, sb2, hbuf, ybuf, out, counts, tlist);
  // GEMM2: experts -> ybuf bf16; shared -> out (exclusive writes, no memset needed)
  moe_gemm<1><<<dim3(8 * MAXTILES), 512, 0, stream>>>(
      x, W1, b1, sW1, sb1, W2, sW2, sb2, hbuf, ybuf, out, counts, tlist);

  finalize_kernel<<<dim3(T_TOK), 256, 0, stream>>>(ybuf, counts, tok2row, tok2g, b2, out);
}